// Round 6
// baseline (384.895 us; speedup 1.0000x reference)
//
#include <hip/hip_runtime.h>
#include <hip/hip_bf16.h>
#include <math.h>

#define BB 2
#define SS 4096
#define DD 512
#define HH 8
#define HD 64
#define MSD (BB*SS*DD)          // 4194304 elements per matrix
#define WSZ (DD*DD)             // 262144 elements per weight

// ws layout (ushort elements):
//   Qb @ 0      [bh][s][hd]  (pre-scaled by log2e/sqrt(512))
//   Kb @ MSD    [bh][s][hd]
//   Vt @ 2*MSD  [bh][hd][s]
//   xb @ 4*MSD  [m][k]
//   Wb @ 5*MSD  3 x [n][k]
#define XOFF (4*(size_t)MSD)
#define WOFF (5*(size_t)MSD)

typedef __attribute__((ext_vector_type(8))) short bf16x8;
typedef __attribute__((ext_vector_type(4))) float f32x4;

__device__ __forceinline__ unsigned short f2bf(float f) {
    unsigned int u = __float_as_uint(f);
    u += 0x7fff + ((u >> 16) & 1);
    return (unsigned short)(u >> 16);
}
__device__ __forceinline__ unsigned int pk2bf(float a, float b) {
    __hip_bfloat162 h = __float22bfloat162_rn(make_float2(a, b));
    union { __hip_bfloat162 h2; unsigned int u; } cv; cv.h2 = h;
    return cv.u;   // low 16 = a, high 16 = b
}

#define GLD16(gsrc, ldst) \
    __builtin_amdgcn_global_load_lds((const __attribute__((address_space(1))) unsigned int*)(gsrc), \
                                     (__attribute__((address_space(3))) unsigned int*)(ldst), 16, 0, 0)

// ---------------------------------------------------------------------------
// fp32 -> bf16 convert: x (MSD els) and Wq|Wk|Wv (3*WSZ els). 8 els/thread.
// ---------------------------------------------------------------------------
__global__ __launch_bounds__(256)
void convert_bf16(const float* __restrict__ x,
                  const float* __restrict__ Wq, const float* __restrict__ Wk,
                  const float* __restrict__ Wv, unsigned short* __restrict__ ws) {
    const int i8 = blockIdx.x*256 + threadIdx.x;
    const float* src; unsigned short* dst; size_t off;
    if (i8 < MSD/8) {
        src = x; dst = ws + XOFF; off = (size_t)i8 * 8;
    } else {
        size_t o = ((size_t)i8 - MSD/8) * 8;
        int wsel = (int)(o / WSZ);
        src = (wsel == 0) ? Wq : (wsel == 1) ? Wk : Wv;
        dst = ws + WOFF + (size_t)wsel*WSZ;
        off = o % WSZ;
    }
    float4 a = *(const float4*)&src[off];
    float4 b = *(const float4*)&src[off+4];
    unsigned short r[8] = { f2bf(a.x), f2bf(a.y), f2bf(a.z), f2bf(a.w),
                            f2bf(b.x), f2bf(b.y), f2bf(b.z), f2bf(b.w) };
    *(bf16x8*)&dst[off] = *(const bf16x8*)r;
}

// ---------------------------------------------------------------------------
// QKV GEMM, bf16 MFMA: C = X @ W^T + b. 128x128 tile, BK=64, 4 waves (2x2).
// z<2: operand-swapped MFMA -> C^T regs; z=2: natural -> C regs.
// Epilogue: C round-trips through LDS (XOR-swizzled) -> fully-coalesced
// 128B-row b128 global stores for both [bh][s][hd] (Q,K) and V^T [bh][hd][s].
// grid (4, 64, 3), block 256.
// ---------------------------------------------------------------------------
__global__ __launch_bounds__(256)
void qkv_mfma(const float* __restrict__ bq, const float* __restrict__ bk,
              const float* __restrict__ bv, unsigned short* __restrict__ ws) {
    const int z = blockIdx.z;
    const unsigned short* Xb = ws + XOFF;
    const unsigned short* Wb = ws + WOFF + (size_t)z*WSZ;
    const float* bias = (z == 0) ? bq : (z == 1) ? bk : bv;
    unsigned short* dst = ws + (size_t)z*MSD;

    __shared__ __align__(16) unsigned short Sh[2*128*64];   // As | Bs, reused as C-tile
    unsigned short* As = Sh;
    unsigned short* Bs = Sh + 128*64;

    const int tid  = threadIdx.x;
    const int w    = tid >> 6, l = tid & 63;
    const int quad = l >> 4,  r16 = l & 15;
    const int wy   = w >> 1,  wx  = w & 1;
    const int m0   = blockIdx.y * 128;
    const int n0   = blockIdx.x * 128;

    const int srow   = l >> 3;
    const int schunk = (l & 7) ^ srow;

    f32x4 acc[4][4];
    #pragma unroll
    for (int i = 0; i < 4; ++i)
        #pragma unroll
        for (int j = 0; j < 4; ++j) acc[i][j] = (f32x4){0.f,0.f,0.f,0.f};

    for (int k0 = 0; k0 < DD; k0 += 64) {
        __syncthreads();
        #pragma unroll
        for (int u = 0; u < 4; ++u) {
            const int r0 = w*32 + u*8;
            GLD16(&Xb[(size_t)(m0 + r0 + srow)*DD + k0 + schunk*8], &As[r0*64]);
            GLD16(&Wb[(size_t)(n0 + r0 + srow)*DD + k0 + schunk*8], &Bs[r0*64]);
        }
        __syncthreads();
        #pragma unroll
        for (int kc = 0; kc < 2; ++kc) {
            bf16x8 a[4], b[4];
            #pragma unroll
            for (int i = 0; i < 4; ++i) {
                const int mr = wy*64 + i*16 + r16;
                a[i] = *(const bf16x8*)&As[mr*64 + (((kc*4+quad) ^ (mr&7))*8)];
                const int nr = wx*64 + i*16 + r16;
                b[i] = *(const bf16x8*)&Bs[nr*64 + (((kc*4+quad) ^ (nr&7))*8)];
            }
            #pragma unroll
            for (int i = 0; i < 4; ++i)
                #pragma unroll
                for (int j = 0; j < 4; ++j) {
                    if (z == 2)
                        acc[i][j] = __builtin_amdgcn_mfma_f32_16x16x32_bf16(a[i], b[j], acc[i][j], 0, 0, 0);
                    else
                        acc[i][j] = __builtin_amdgcn_mfma_f32_16x16x32_bf16(b[j], a[i], acc[i][j], 0, 0, 0);
                }
        }
    }

    __syncthreads();   // k-loop LDS reads done; reuse Sh as 128x128 C-tile

    const float qscale = 0.04419417382415922f * 1.4426950408889634f; // 1/sqrt(512)*log2e
    if (z == 2) {
        // natural C: lane holds C[m = wy*64+i*16+quad*4+reg][n = wx*64+j*16+r16]
        // store TRANSPOSED into Sh[n][m] (4 consec m per uint2)
        #pragma unroll
        for (int j = 0; j < 4; ++j) {
            const int nloc = wx*64 + j*16 + r16;
            const float bz = bias[n0 + nloc];
            #pragma unroll
            for (int i = 0; i < 4; ++i) {
                const int chunk = wy*8 + i*2 + (quad>>1);
                const int off   = (quad & 1) * 4;
                unsigned short r4[4];
                #pragma unroll
                for (int reg = 0; reg < 4; ++reg)
                    r4[reg] = f2bf(acc[i][j][reg] + bz);
                *(uint2*)&Sh[nloc*128 + ((chunk ^ (nloc & 7))*8) + off] = *(const uint2*)r4;
            }
        }
    } else {
        // swapped C^T: lane holds C^T[n = wx*64+j*16+quad*4+reg][m = wy*64+i*16+r16]
        // store into Sh[m][n] (4 consec n per uint2)
        #pragma unroll
        for (int j = 0; j < 4; ++j) {
            const int nbase = wx*64 + j*16 + quad*4;
            const float4 bz4 = *(const float4*)&bias[n0 + nbase];
            const int chunk = wx*8 + j*2 + (quad>>1);
            const int off   = (quad & 1) * 4;
            #pragma unroll
            for (int i = 0; i < 4; ++i) {
                const int mloc = wy*64 + i*16 + r16;
                float v0 = acc[i][j][0] + bz4.x;
                float v1 = acc[i][j][1] + bz4.y;
                float v2 = acc[i][j][2] + bz4.z;
                float v3 = acc[i][j][3] + bz4.w;
                if (z == 0) { v0 *= qscale; v1 *= qscale; v2 *= qscale; v3 *= qscale; }
                unsigned short r4[4] = { f2bf(v0), f2bf(v1), f2bf(v2), f2bf(v3) };
                *(uint2*)&Sh[mloc*128 + ((chunk ^ (mloc & 7))*8) + off] = *(const uint2*)r4;
            }
        }
    }
    __syncthreads();

    // coalesced stores: each thread owns one 128B half-row
    const int row = tid >> 1, half = tid & 1;
    if (z == 2) {
        const int ng = n0 + row;                 // hd-row of V^T
        const int h = ng >> 6, hd = ng & 63;
        const int b_ = m0 >> 12, s0_ = m0 & (SS-1);
        const size_t gbase = ((size_t)(b_*HH + h)*HD + hd)*SS + s0_ + half*64;
        #pragma unroll
        for (int c8 = 0; c8 < 8; ++c8) {
            bf16x8 v = *(const bf16x8*)&Sh[row*128 + (((half*8 + c8) ^ (row & 7))*8)];
            *(bf16x8*)&dst[gbase + c8*8] = v;
        }
    } else {
        const int mg = m0 + row;                 // s-row of Q/K
        const int b_ = mg >> 12, s_ = mg & (SS-1);
        const int hg = (n0 >> 6) + half;
        const size_t gbase = ((size_t)(b_*HH + hg)*SS + s_)*HD;
        #pragma unroll
        for (int c8 = 0; c8 < 8; ++c8) {
            bf16x8 v = *(const bf16x8*)&Sh[row*128 + (((half*8 + c8) ^ (row & 7))*8)];
            *(bf16x8*)&dst[gbase + c8*8] = v;
        }
    }
}

// ---------------------------------------------------------------------------
// MFMA flash attention, additive K-split. Block = 4 waves on ONE 64-q chunk;
// wave w handles j-tiles jt = w, w+4, ... (fixed-max softmax -> partials are
// additive, no rescale). Per-tile math identical to round 5 (direct-global
// K/V A-frags, wave-private P round-trip). End: 3-step LDS tree combines the
// 4 waves' O/l partials; wave 0 stores. grid 1024 (bh-major), block 256.
// ---------------------------------------------------------------------------
__global__ __launch_bounds__(256, 3)
void attn_mfma(const unsigned short* __restrict__ ws, float* __restrict__ out) {
    const int bh  = blockIdx.x >> 6;
    const int qc  = 63 - (blockIdx.x & 63);     // heavy-first within each bh
    const int qlo = qc * 64;
    const int tid = threadIdx.x;
    const int w   = tid >> 6, l = tid & 63;
    const int quad = l >> 4, r16 = l & 15;

    const unsigned short* Qg  = ws;             // pre-scaled by log2e/sqrt(512)
    const unsigned short* Kg  = ws + (size_t)MSD;
    const unsigned short* Vtg = ws + 2*(size_t)MSD;

    __shared__ __align__(16) unsigned int PsAll[4*2304];  // 4 waves x 64q x 36 dwords
    __shared__ float Lsh[4][64];
    unsigned int* PsW = PsAll + w*2304;

    // Q B-frags (same for all 4 waves): Q[q = qlo+nt*16+r16][d = kc*32+quad*8+j]
    bf16x8 bqf[4][2];
    #pragma unroll
    for (int nt = 0; nt < 4; ++nt)
        #pragma unroll
        for (int kc = 0; kc < 2; ++kc)
            bqf[nt][kc] = *(const bf16x8*)&Qg[((size_t)bh*SS + qlo + nt*16 + r16)*HD + kc*32 + quad*8];

    f32x4 od[4][4];   // O^T partial: [mt -> d][nt -> q]
    #pragma unroll
    for (int mt = 0; mt < 4; ++mt)
        #pragma unroll
        for (int nt = 0; nt < 4; ++nt) od[mt][nt] = (f32x4){0.f,0.f,0.f,0.f};
    float lsum[4] = {0.f, 0.f, 0.f, 0.f};

    const size_t kbase = (size_t)bh*SS*HD;
    const size_t vbase = (size_t)bh*HD*SS;

    for (int jt = w; jt <= qc; jt += 4) {
        const int jb = jt*64;
        const bool diag = (jt == qc);

        // ---- S^T = K Q^T, per 16-key slab: mfma -> mask -> exp2 -> pack -> LDS
        #pragma unroll
        for (int mt = 0; mt < 4; ++mt) {
            bf16x8 kf0 = *(const bf16x8*)&Kg[kbase + (size_t)(jb + mt*16 + r16)*HD + quad*8];
            bf16x8 kf1 = *(const bf16x8*)&Kg[kbase + (size_t)(jb + mt*16 + r16)*HD + 32 + quad*8];
            f32x4 z[4];
            #pragma unroll
            for (int nt = 0; nt < 4; ++nt) z[nt] = (f32x4){0.f,0.f,0.f,0.f};
            #pragma unroll
            for (int nt = 0; nt < 4; ++nt)
                z[nt] = __builtin_amdgcn_mfma_f32_16x16x32_bf16(kf0, bqf[nt][0], z[nt], 0, 0, 0);
            #pragma unroll
            for (int nt = 0; nt < 4; ++nt)
                z[nt] = __builtin_amdgcn_mfma_f32_16x16x32_bf16(kf1, bqf[nt][1], z[nt], 0, 0, 0);

            if (diag) {   // key_local mt*16+quad*4+reg > q_local nt*16+r16
                #pragma unroll
                for (int nt = 0; nt < 4; ++nt)
                    #pragma unroll
                    for (int reg = 0; reg < 4; ++reg)
                        if (mt*16 + quad*4 + reg > nt*16 + r16)
                            z[nt][reg] = -1e30f;
            }

            #pragma unroll
            for (int nt = 0; nt < 4; ++nt) {
                #pragma unroll
                for (int reg = 0; reg < 4; ++reg) {
                    z[nt][reg] = exp2f(z[nt][reg]);
                    lsum[nt] += z[nt][reg];
                }
                const int q = nt*16 + r16;
                PsW[q*36 + mt*8 + quad*2 + 0] = pk2bf(z[nt][0], z[nt][1]);
                PsW[q*36 + mt*8 + quad*2 + 1] = pk2bf(z[nt][2], z[nt][3]);
            }
        }

        asm volatile("s_waitcnt lgkmcnt(0)" ::: "memory");  // wave-private round-trip

        // ---- read P B-frags (natural key order), then O^T += V^T P^T
        bf16x8 pf[4][2];
        #pragma unroll
        for (int nt = 0; nt < 4; ++nt)
            #pragma unroll
            for (int kc = 0; kc < 2; ++kc)
                pf[nt][kc] = *(const bf16x8*)&PsW[(nt*16 + r16)*36 + kc*16 + quad*4];

        #pragma unroll
        for (int mt = 0; mt < 4; ++mt) {
            bf16x8 vf0 = *(const bf16x8*)&Vtg[vbase + (size_t)(mt*16 + r16)*SS + jb + quad*8];
            bf16x8 vf1 = *(const bf16x8*)&Vtg[vbase + (size_t)(mt*16 + r16)*SS + jb + 32 + quad*8];
            #pragma unroll
            for (int nt = 0; nt < 4; ++nt)
                od[mt][nt] = __builtin_amdgcn_mfma_f32_16x16x32_bf16(vf0, pf[nt][0], od[mt][nt], 0, 0, 0);
            #pragma unroll
            for (int nt = 0; nt < 4; ++nt)
                od[mt][nt] = __builtin_amdgcn_mfma_f32_16x16x32_bf16(vf1, pf[nt][1], od[mt][nt], 0, 0, 0);
        }
    }

    // ---- cross-wave combine (additive; LDS tree reusing Ps space) ----
    // intra-wave l: sum quad partials
    #pragma unroll
    for (int nt = 0; nt < 4; ++nt) {
        lsum[nt] += __shfl_xor(lsum[nt], 16);
        lsum[nt] += __shfl_xor(lsum[nt], 32);
    }
    __syncthreads();
    if (w >= 2) {   // waves 2,3 dump od (region: 64 lanes x 68 dwords, b128-clean)
        const int base = (w-2)*4352 + l*68;
        #pragma unroll
        for (int mt = 0; mt < 4; ++mt)
            #pragma unroll
            for (int nt = 0; nt < 4; ++nt)
                *(f32x4*)&PsAll[base + (mt*4+nt)*4] = od[mt][nt];
    }
    if (l < 16) {
        #pragma unroll
        for (int nt = 0; nt < 4; ++nt) Lsh[w][nt*16 + l] = lsum[nt];
    }
    __syncthreads();
    if (w < 2) {    // wave 0 += wave 2, wave 1 += wave 3
        const int base = w*4352 + l*68;
        #pragma unroll
        for (int mt = 0; mt < 4; ++mt)
            #pragma unroll
            for (int nt = 0; nt < 4; ++nt)
                od[mt][nt] += *(const f32x4*)&PsAll[base + (mt*4+nt)*4];
    }
    __syncthreads();
    if (w == 1) {
        const int base = l*68;
        #pragma unroll
        for (int mt = 0; mt < 4; ++mt)
            #pragma unroll
            for (int nt = 0; nt < 4; ++nt)
                *(f32x4*)&PsAll[base + (mt*4+nt)*4] = od[mt][nt];
    }
    __syncthreads();
    if (w == 0) {
        const int base = l*68;
        #pragma unroll
        for (int mt = 0; mt < 4; ++mt)
            #pragma unroll
            for (int nt = 0; nt < 4; ++nt)
                od[mt][nt] += *(const f32x4*)&PsAll[base + (mt*4+nt)*4];

        const int b_ = bh >> 3, h = bh & 7;
        #pragma unroll
        for (int nt = 0; nt < 4; ++nt) {
            const float lt = Lsh[0][nt*16 + r16] + Lsh[1][nt*16 + r16]
                           + Lsh[2][nt*16 + r16] + Lsh[3][nt*16 + r16];
            const float inv = 1.0f / lt;
            const int q = qlo + nt*16 + r16;
            float* op = out + ((size_t)(b_*SS + q))*DD + h*HD;
            #pragma unroll
            for (int mt = 0; mt < 4; ++mt) {
                float4 t;
                t.x = od[mt][nt][0]*inv; t.y = od[mt][nt][1]*inv;
                t.z = od[mt][nt][2]*inv; t.w = od[mt][nt][3]*inv;
                *(float4*)&op[mt*16 + quad*4] = t;
            }
        }
    }
}

extern "C" void kernel_launch(void* const* d_in, const int* in_sizes, int n_in,
                              void* d_out, int out_size, void* d_ws, size_t ws_size,
                              hipStream_t stream) {
    const float* x  = (const float*)d_in[0];
    const float* Wq = (const float*)d_in[1];
    const float* bq = (const float*)d_in[2];
    const float* Wk = (const float*)d_in[3];
    const float* bk = (const float*)d_in[4];
    const float* Wv = (const float*)d_in[5];
    const float* bv = (const float*)d_in[6];
    float* out = (float*)d_out;
    unsigned short* ws = (unsigned short*)d_ws;

    const int nconv = (MSD/8 + 3*WSZ/8 + 255) / 256;
    convert_bf16<<<nconv, 256, 0, stream>>>(x, Wq, Wk, Wv, ws);

    dim3 ggrid(DD/128, (BB*SS)/128, 3);           // (4, 64, 3)
    qkv_mfma<<<ggrid, 256, 0, stream>>>(bq, bk, bv, ws);

    attn_mfma<<<1024, 256, 0, stream>>>(ws, out);
}

// Round 7
// 254.657 us; speedup vs baseline: 1.5114x; 1.5114x over previous
//
#include <hip/hip_runtime.h>
#include <hip/hip_bf16.h>
#include <math.h>

#define BB 2
#define SS 4096
#define DD 512
#define HH 8
#define HD 64
#define MSD (BB*SS*DD)          // 4194304 elements per matrix
#define WSZ (DD*DD)             // 262144 elements per weight

// ws layout (ushort elements):
//   Qb @ 0      [bh][s][hd]  (pre-scaled by log2e/sqrt(512))
//   Kb @ MSD    [bh][s][hd]
//   Vt @ 2*MSD  [bh][hd][s]
//   xb @ 4*MSD  [m][k]
//   Wb @ 5*MSD  3 x [n][k]
#define XOFF (4*(size_t)MSD)
#define WOFF (5*(size_t)MSD)

typedef __attribute__((ext_vector_type(8))) short bf16x8;
typedef __attribute__((ext_vector_type(4))) float f32x4;

__device__ __forceinline__ unsigned short f2bf(float f) {
    unsigned int u = __float_as_uint(f);
    u += 0x7fff + ((u >> 16) & 1);
    return (unsigned short)(u >> 16);
}
__device__ __forceinline__ unsigned int pk2bf(float a, float b) {
    __hip_bfloat162 h = __float22bfloat162_rn(make_float2(a, b));
    union { __hip_bfloat162 h2; unsigned int u; } cv; cv.h2 = h;
    return cv.u;   // low 16 = a, high 16 = b
}

#define GLD16(gsrc, ldst) \
    __builtin_amdgcn_global_load_lds((const __attribute__((address_space(1))) unsigned int*)(gsrc), \
                                     (__attribute__((address_space(3))) unsigned int*)(ldst), 16, 0, 0)

// ---------------------------------------------------------------------------
// fp32 -> bf16 convert: x (MSD els) and Wq|Wk|Wv (3*WSZ els). 8 els/thread.
// ---------------------------------------------------------------------------
__global__ __launch_bounds__(256)
void convert_bf16(const float* __restrict__ x,
                  const float* __restrict__ Wq, const float* __restrict__ Wk,
                  const float* __restrict__ Wv, unsigned short* __restrict__ ws) {
    const int i8 = blockIdx.x*256 + threadIdx.x;
    const float* src; unsigned short* dst; size_t off;
    if (i8 < MSD/8) {
        src = x; dst = ws + XOFF; off = (size_t)i8 * 8;
    } else {
        size_t o = ((size_t)i8 - MSD/8) * 8;
        int wsel = (int)(o / WSZ);
        src = (wsel == 0) ? Wq : (wsel == 1) ? Wk : Wv;
        dst = ws + WOFF + (size_t)wsel*WSZ;
        off = o % WSZ;
    }
    float4 a = *(const float4*)&src[off];
    float4 b = *(const float4*)&src[off+4];
    unsigned short r[8] = { f2bf(a.x), f2bf(a.y), f2bf(a.z), f2bf(a.w),
                            f2bf(b.x), f2bf(b.y), f2bf(b.z), f2bf(b.w) };
    *(bf16x8*)&dst[off] = *(const bf16x8*)r;
}

// ---------------------------------------------------------------------------
// QKV GEMM, bf16 MFMA: C = X @ W^T + b. 128x128 tile, BK=64, 4 waves (2x2).
// z<2: operand-swapped MFMA -> C^T regs; z=2: natural -> C regs.
// Epilogue: C round-trips through LDS (XOR-swizzled) -> fully-coalesced
// 128B-row b128 global stores for both [bh][s][hd] (Q,K) and V^T [bh][hd][s].
// grid (4, 64, 3), block 256.
// ---------------------------------------------------------------------------
__global__ __launch_bounds__(256)
void qkv_mfma(const float* __restrict__ bq, const float* __restrict__ bk,
              const float* __restrict__ bv, unsigned short* __restrict__ ws) {
    const int z = blockIdx.z;
    const unsigned short* Xb = ws + XOFF;
    const unsigned short* Wb = ws + WOFF + (size_t)z*WSZ;
    const float* bias = (z == 0) ? bq : (z == 1) ? bk : bv;
    unsigned short* dst = ws + (size_t)z*MSD;

    __shared__ __align__(16) unsigned short Sh[2*128*64];   // As | Bs, reused as C-tile
    unsigned short* As = Sh;
    unsigned short* Bs = Sh + 128*64;

    const int tid  = threadIdx.x;
    const int w    = tid >> 6, l = tid & 63;
    const int quad = l >> 4,  r16 = l & 15;
    const int wy   = w >> 1,  wx  = w & 1;
    const int m0   = blockIdx.y * 128;
    const int n0   = blockIdx.x * 128;

    const int srow   = l >> 3;
    const int schunk = (l & 7) ^ srow;

    f32x4 acc[4][4];
    #pragma unroll
    for (int i = 0; i < 4; ++i)
        #pragma unroll
        for (int j = 0; j < 4; ++j) acc[i][j] = (f32x4){0.f,0.f,0.f,0.f};

    for (int k0 = 0; k0 < DD; k0 += 64) {
        __syncthreads();
        #pragma unroll
        for (int u = 0; u < 4; ++u) {
            const int r0 = w*32 + u*8;
            GLD16(&Xb[(size_t)(m0 + r0 + srow)*DD + k0 + schunk*8], &As[r0*64]);
            GLD16(&Wb[(size_t)(n0 + r0 + srow)*DD + k0 + schunk*8], &Bs[r0*64]);
        }
        __syncthreads();
        #pragma unroll
        for (int kc = 0; kc < 2; ++kc) {
            bf16x8 a[4], b[4];
            #pragma unroll
            for (int i = 0; i < 4; ++i) {
                const int mr = wy*64 + i*16 + r16;
                a[i] = *(const bf16x8*)&As[mr*64 + (((kc*4+quad) ^ (mr&7))*8)];
                const int nr = wx*64 + i*16 + r16;
                b[i] = *(const bf16x8*)&Bs[nr*64 + (((kc*4+quad) ^ (nr&7))*8)];
            }
            #pragma unroll
            for (int i = 0; i < 4; ++i)
                #pragma unroll
                for (int j = 0; j < 4; ++j) {
                    if (z == 2)
                        acc[i][j] = __builtin_amdgcn_mfma_f32_16x16x32_bf16(a[i], b[j], acc[i][j], 0, 0, 0);
                    else
                        acc[i][j] = __builtin_amdgcn_mfma_f32_16x16x32_bf16(b[j], a[i], acc[i][j], 0, 0, 0);
                }
        }
    }

    __syncthreads();   // k-loop LDS reads done; reuse Sh as 128x128 C-tile

    const float qscale = 0.04419417382415922f * 1.4426950408889634f; // 1/sqrt(512)*log2e
    if (z == 2) {
        // natural C: lane holds C[m = wy*64+i*16+quad*4+reg][n = wx*64+j*16+r16]
        // store TRANSPOSED into Sh[n][m] (4 consec m per uint2)
        #pragma unroll
        for (int j = 0; j < 4; ++j) {
            const int nloc = wx*64 + j*16 + r16;
            const float bz = bias[n0 + nloc];
            #pragma unroll
            for (int i = 0; i < 4; ++i) {
                const int chunk = wy*8 + i*2 + (quad>>1);
                const int off   = (quad & 1) * 4;
                unsigned short r4[4];
                #pragma unroll
                for (int reg = 0; reg < 4; ++reg)
                    r4[reg] = f2bf(acc[i][j][reg] + bz);
                *(uint2*)&Sh[nloc*128 + ((chunk ^ (nloc & 7))*8) + off] = *(const uint2*)r4;
            }
        }
    } else {
        // swapped C^T: lane holds C^T[n = wx*64+j*16+quad*4+reg][m = wy*64+i*16+r16]
        // store into Sh[m][n] (4 consec n per uint2)
        #pragma unroll
        for (int j = 0; j < 4; ++j) {
            const int nbase = wx*64 + j*16 + quad*4;
            const float4 bz4 = *(const float4*)&bias[n0 + nbase];
            const int chunk = wx*8 + j*2 + (quad>>1);
            const int off   = (quad & 1) * 4;
            #pragma unroll
            for (int i = 0; i < 4; ++i) {
                const int mloc = wy*64 + i*16 + r16;
                float v0 = acc[i][j][0] + bz4.x;
                float v1 = acc[i][j][1] + bz4.y;
                float v2 = acc[i][j][2] + bz4.z;
                float v3 = acc[i][j][3] + bz4.w;
                if (z == 0) { v0 *= qscale; v1 *= qscale; v2 *= qscale; v3 *= qscale; }
                unsigned short r4[4] = { f2bf(v0), f2bf(v1), f2bf(v2), f2bf(v3) };
                *(uint2*)&Sh[mloc*128 + ((chunk ^ (mloc & 7))*8) + off] = *(const uint2*)r4;
            }
        }
    }
    __syncthreads();

    // coalesced stores: each thread owns one 128B half-row
    const int row = tid >> 1, half = tid & 1;
    if (z == 2) {
        const int ng = n0 + row;                 // hd-row of V^T
        const int h = ng >> 6, hd = ng & 63;
        const int b_ = m0 >> 12, s0_ = m0 & (SS-1);
        const size_t gbase = ((size_t)(b_*HH + h)*HD + hd)*SS + s0_ + half*64;
        #pragma unroll
        for (int c8 = 0; c8 < 8; ++c8) {
            bf16x8 v = *(const bf16x8*)&Sh[row*128 + (((half*8 + c8) ^ (row & 7))*8)];
            *(bf16x8*)&dst[gbase + c8*8] = v;
        }
    } else {
        const int mg = m0 + row;                 // s-row of Q/K
        const int b_ = mg >> 12, s_ = mg & (SS-1);
        const int hg = (n0 >> 6) + half;
        const size_t gbase = ((size_t)(b_*HH + hg)*SS + s_)*HD;
        #pragma unroll
        for (int c8 = 0; c8 < 8; ++c8) {
            bf16x8 v = *(const bf16x8*)&Sh[row*128 + (((half*8 + c8) ^ (row & 7))*8)];
            *(bf16x8*)&dst[gbase + c8*8] = v;
        }
    }
}

// ---------------------------------------------------------------------------
// Pipelined barrier-free MFMA flash attention. One wave per block, 32 q/wave,
// wave owns the full causal key-prefix. Per 64-key tile: S^T = K Q^T (direct-
// global K A-frags), exp2 (fixed max, scores bounded), P via wave-private LDS
// (stride-36-dword rows), O^T += V^T P^T. K(t+1) loads issue right after S(t)
// consumes K(t); V(t+1) after PV(t) -> ~1 tile of latency hiding, no barriers.
// grid 2048 (bh in low 4 bits; heavy chunks first), block 64.
// ---------------------------------------------------------------------------
__global__ __launch_bounds__(64)
void attn_mfma(const unsigned short* __restrict__ ws, float* __restrict__ out) {
    const int bh   = blockIdx.x & 15;
    const int qi   = 127 - (blockIdx.x >> 4);   // 0..127, heavy-first
    const int qlo  = qi * 32;
    const int l    = threadIdx.x;
    const int quad = l >> 4, r16 = l & 15;
    const int ntiles = (qi >> 1) + 1;

    const unsigned short* Qg  = ws;             // pre-scaled by log2e/sqrt(512)
    const unsigned short* Kg  = ws + (size_t)MSD;
    const unsigned short* Vtg = ws + 2*(size_t)MSD;

    __shared__ __align__(16) unsigned int Ps[32*36];   // 4.5 KB, stride 36 dwords/q

    // Q B-frags: lane holds Q[q = qlo+nt*16+r16][d = kc*32+quad*8+j]
    bf16x8 bqf[2][2];
    #pragma unroll
    for (int nt = 0; nt < 2; ++nt)
        #pragma unroll
        for (int kc = 0; kc < 2; ++kc)
            bqf[nt][kc] = *(const bf16x8*)&Qg[((size_t)bh*SS + qlo + nt*16 + r16)*HD + kc*32 + quad*8];

    f32x4 od[4][2];   // O^T accum: [mt -> d][nt -> q]
    #pragma unroll
    for (int mt = 0; mt < 4; ++mt)
        #pragma unroll
        for (int nt = 0; nt < 2; ++nt) od[mt][nt] = (f32x4){0.f,0.f,0.f,0.f};
    float lsum[2] = {0.f, 0.f};

    const size_t kbase = (size_t)bh*SS*HD;
    const size_t vbase = (size_t)bh*HD*SS;

    // prefetch tile 0
    bf16x8 kf[4][2], vf[4][2];
    #pragma unroll
    for (int mt = 0; mt < 4; ++mt)
        #pragma unroll
        for (int kc = 0; kc < 2; ++kc) {
            kf[mt][kc] = *(const bf16x8*)&Kg [kbase + (size_t)(mt*16 + r16)*HD + kc*32 + quad*8];
            vf[mt][kc] = *(const bf16x8*)&Vtg[vbase + (size_t)(mt*16 + r16)*SS + kc*32 + quad*8];
        }

    for (int t = 0; t < ntiles; ++t) {
        const int jb = t*64;

        // ---- S^T = K Q^T : lane holds S^T[key = mt*16+quad*4+reg][q = nt*16+r16]
        f32x4 z[4][2];
        #pragma unroll
        for (int mt = 0; mt < 4; ++mt)
            #pragma unroll
            for (int nt = 0; nt < 2; ++nt) z[mt][nt] = (f32x4){0.f,0.f,0.f,0.f};
        #pragma unroll
        for (int mt = 0; mt < 4; ++mt)
            #pragma unroll
            for (int kc = 0; kc < 2; ++kc)
                #pragma unroll
                for (int nt = 0; nt < 2; ++nt)
                    z[mt][nt] = __builtin_amdgcn_mfma_f32_16x16x32_bf16(kf[mt][kc], bqf[nt][kc], z[mt][nt], 0, 0, 0);

        // prefetch K(t+1) — kf regs now dead, loads overlap exp2/LDS/PV below
        if (t + 1 < ntiles) {
            #pragma unroll
            for (int mt = 0; mt < 4; ++mt)
                #pragma unroll
                for (int kc = 0; kc < 2; ++kc)
                    kf[mt][kc] = *(const bf16x8*)&Kg[kbase + (size_t)(jb + 64 + mt*16 + r16)*HD + kc*32 + quad*8];
        }

        if (t == ntiles - 1) {   // causal mask, diagonal tile only
            const int qoff = 32*(qi & 1);   // even qi: upper 32 keys fully masked
            #pragma unroll
            for (int mt = 0; mt < 4; ++mt)
                #pragma unroll
                for (int nt = 0; nt < 2; ++nt)
                    #pragma unroll
                    for (int reg = 0; reg < 4; ++reg)
                        if (mt*16 + quad*4 + reg > nt*16 + r16 + qoff)
                            z[mt][nt][reg] = -1e30f;
        }

        // ---- P = exp2(z); accumulate l; pack key-pairs -> b64 LDS stores
        #pragma unroll
        for (int mt = 0; mt < 4; ++mt)
            #pragma unroll
            for (int nt = 0; nt < 2; ++nt) {
                #pragma unroll
                for (int reg = 0; reg < 4; ++reg) {
                    z[mt][nt][reg] = exp2f(z[mt][nt][reg]);
                    lsum[nt] += z[mt][nt][reg];
                }
                uint2 pk;
                pk.x = pk2bf(z[mt][nt][0], z[mt][nt][1]);
                pk.y = pk2bf(z[mt][nt][2], z[mt][nt][3]);
                *(uint2*)&Ps[(nt*16 + r16)*36 + mt*8 + quad*2] = pk;
            }

        asm volatile("s_waitcnt lgkmcnt(0)" ::: "memory");  // wave-private round-trip

        // ---- O^T += V^T P^T
        bf16x8 pf[2][2];
        #pragma unroll
        for (int nt = 0; nt < 2; ++nt)
            #pragma unroll
            for (int kc = 0; kc < 2; ++kc)
                pf[nt][kc] = *(const bf16x8*)&Ps[(nt*16 + r16)*36 + kc*16 + quad*4];

        #pragma unroll
        for (int mt = 0; mt < 4; ++mt)
            #pragma unroll
            for (int kc = 0; kc < 2; ++kc)
                #pragma unroll
                for (int nt = 0; nt < 2; ++nt)
                    od[mt][nt] = __builtin_amdgcn_mfma_f32_16x16x32_bf16(vf[mt][kc], pf[nt][kc], od[mt][nt], 0, 0, 0);

        // prefetch V(t+1) — vf regs now dead; ~1 full tile until use
        if (t + 1 < ntiles) {
            #pragma unroll
            for (int mt = 0; mt < 4; ++mt)
                #pragma unroll
                for (int kc = 0; kc < 2; ++kc)
                    vf[mt][kc] = *(const bf16x8*)&Vtg[vbase + (size_t)(mt*16 + r16)*SS + jb + 64 + kc*32 + quad*8];
        }
    }

    // ---- l: sum the 4 quad-partials per q
    #pragma unroll
    for (int nt = 0; nt < 2; ++nt) {
        lsum[nt] += __shfl_xor(lsum[nt], 16);
        lsum[nt] += __shfl_xor(lsum[nt], 32);
    }

    const int b_ = bh >> 3, h = bh & 7;
    #pragma unroll
    for (int nt = 0; nt < 2; ++nt) {
        const float inv = 1.0f / lsum[nt];
        const int q = qlo + nt*16 + r16;
        float* op = out + ((size_t)(b_*SS + q))*DD + h*HD;
        #pragma unroll
        for (int mt = 0; mt < 4; ++mt) {
            float4 tt;
            tt.x = od[mt][nt][0]*inv; tt.y = od[mt][nt][1]*inv;
            tt.z = od[mt][nt][2]*inv; tt.w = od[mt][nt][3]*inv;
            *(float4*)&op[mt*16 + quad*4] = tt;
        }
    }
}

extern "C" void kernel_launch(void* const* d_in, const int* in_sizes, int n_in,
                              void* d_out, int out_size, void* d_ws, size_t ws_size,
                              hipStream_t stream) {
    const float* x  = (const float*)d_in[0];
    const float* Wq = (const float*)d_in[1];
    const float* bq = (const float*)d_in[2];
    const float* Wk = (const float*)d_in[3];
    const float* bk = (const float*)d_in[4];
    const float* Wv = (const float*)d_in[5];
    const float* bv = (const float*)d_in[6];
    float* out = (float*)d_out;
    unsigned short* ws = (unsigned short*)d_ws;

    const int nconv = (MSD/8 + 3*WSZ/8 + 255) / 256;
    convert_bf16<<<nconv, 256, 0, stream>>>(x, Wq, Wk, Wv, ws);

    dim3 ggrid(DD/128, (BB*SS)/128, 3);           // (4, 64, 3)
    qkv_mfma<<<ggrid, 256, 0, stream>>>(bq, bk, bv, ws);

    attn_mfma<<<2048, 64, 0, stream>>>(ws, out);
}

// Round 8
// 219.497 us; speedup vs baseline: 1.7535x; 1.1602x over previous
//
#include <hip/hip_runtime.h>
#include <hip/hip_bf16.h>
#include <math.h>

#define BB 2
#define SS 4096
#define DD 512
#define HH 8
#define HD 64
#define MSD (BB*SS*DD)          // 4194304 elements per matrix
#define WSZ (DD*DD)             // 262144 elements per weight

// ws layout (ushort elements):
//   Qb @ 0      [bh][s][hd]  (pre-scaled by log2e/sqrt(512))
//   Kb @ MSD    [bh][s][hd]
//   Vt @ 2*MSD  [bh][hd][s]
//   xb @ 4*MSD  [m][k]
//   Wb @ 5*MSD  3 x [n][k]
#define XOFF (4*(size_t)MSD)
#define WOFF (5*(size_t)MSD)

typedef __attribute__((ext_vector_type(8))) short bf16x8;
typedef __attribute__((ext_vector_type(4))) float f32x4;

__device__ __forceinline__ unsigned short f2bf(float f) {
    unsigned int u = __float_as_uint(f);
    u += 0x7fff + ((u >> 16) & 1);
    return (unsigned short)(u >> 16);
}
__device__ __forceinline__ unsigned int pk2bf(float a, float b) {
    __hip_bfloat162 h = __float22bfloat162_rn(make_float2(a, b));
    union { __hip_bfloat162 h2; unsigned int u; } cv; cv.h2 = h;
    return cv.u;   // low 16 = a, high 16 = b
}

#define GLD16(gsrc, ldst) \
    __builtin_amdgcn_global_load_lds((const __attribute__((address_space(1))) unsigned int*)(gsrc), \
                                     (__attribute__((address_space(3))) unsigned int*)(ldst), 16, 0, 0)

// ---------------------------------------------------------------------------
// fp32 -> bf16 convert: x (MSD els) and Wq|Wk|Wv (3*WSZ els). 8 els/thread.
// ---------------------------------------------------------------------------
__global__ __launch_bounds__(256)
void convert_bf16(const float* __restrict__ x,
                  const float* __restrict__ Wq, const float* __restrict__ Wk,
                  const float* __restrict__ Wv, unsigned short* __restrict__ ws) {
    const int i8 = blockIdx.x*256 + threadIdx.x;
    const float* src; unsigned short* dst; size_t off;
    if (i8 < MSD/8) {
        src = x; dst = ws + XOFF; off = (size_t)i8 * 8;
    } else {
        size_t o = ((size_t)i8 - MSD/8) * 8;
        int wsel = (int)(o / WSZ);
        src = (wsel == 0) ? Wq : (wsel == 1) ? Wk : Wv;
        dst = ws + WOFF + (size_t)wsel*WSZ;
        off = o % WSZ;
    }
    float4 a = *(const float4*)&src[off];
    float4 b = *(const float4*)&src[off+4];
    unsigned short r[8] = { f2bf(a.x), f2bf(a.y), f2bf(a.z), f2bf(a.w),
                            f2bf(b.x), f2bf(b.y), f2bf(b.z), f2bf(b.w) };
    *(bf16x8*)&dst[off] = *(const bf16x8*)r;
}

// ---------------------------------------------------------------------------
// QKV GEMM, bf16 MFMA: C = X @ W^T + b. 128x128 tile, BK=64, 4 waves (2x2).
// z<2: operand-swapped MFMA -> C^T regs; z=2: natural -> C regs.
// Epilogue: C round-trips through LDS (XOR-swizzled), then COALESCED stores:
// consecutive lanes write consecutive 16B chunks (1KB-contiguous per inst for
// Q/K; 256B runs for V^T). grid (4, 64, 3), block 256.
// ---------------------------------------------------------------------------
__global__ __launch_bounds__(256)
void qkv_mfma(const float* __restrict__ bq, const float* __restrict__ bk,
              const float* __restrict__ bv, unsigned short* __restrict__ ws) {
    const int z = blockIdx.z;
    const unsigned short* Xb = ws + XOFF;
    const unsigned short* Wb = ws + WOFF + (size_t)z*WSZ;
    const float* bias = (z == 0) ? bq : (z == 1) ? bk : bv;
    unsigned short* dst = ws + (size_t)z*MSD;

    __shared__ __align__(16) unsigned short Sh[2*128*64];   // As | Bs, reused as C-tile
    unsigned short* As = Sh;
    unsigned short* Bs = Sh + 128*64;

    const int tid  = threadIdx.x;
    const int w    = tid >> 6, l = tid & 63;
    const int quad = l >> 4,  r16 = l & 15;
    const int wy   = w >> 1,  wx  = w & 1;
    const int m0   = blockIdx.y * 128;
    const int n0   = blockIdx.x * 128;

    const int srow   = l >> 3;
    const int schunk = (l & 7) ^ srow;

    f32x4 acc[4][4];
    #pragma unroll
    for (int i = 0; i < 4; ++i)
        #pragma unroll
        for (int j = 0; j < 4; ++j) acc[i][j] = (f32x4){0.f,0.f,0.f,0.f};

    for (int k0 = 0; k0 < DD; k0 += 64) {
        __syncthreads();
        #pragma unroll
        for (int u = 0; u < 4; ++u) {
            const int r0 = w*32 + u*8;
            GLD16(&Xb[(size_t)(m0 + r0 + srow)*DD + k0 + schunk*8], &As[r0*64]);
            GLD16(&Wb[(size_t)(n0 + r0 + srow)*DD + k0 + schunk*8], &Bs[r0*64]);
        }
        __syncthreads();
        #pragma unroll
        for (int kc = 0; kc < 2; ++kc) {
            bf16x8 a[4], b[4];
            #pragma unroll
            for (int i = 0; i < 4; ++i) {
                const int mr = wy*64 + i*16 + r16;
                a[i] = *(const bf16x8*)&As[mr*64 + (((kc*4+quad) ^ (mr&7))*8)];
                const int nr = wx*64 + i*16 + r16;
                b[i] = *(const bf16x8*)&Bs[nr*64 + (((kc*4+quad) ^ (nr&7))*8)];
            }
            #pragma unroll
            for (int i = 0; i < 4; ++i)
                #pragma unroll
                for (int j = 0; j < 4; ++j) {
                    if (z == 2)
                        acc[i][j] = __builtin_amdgcn_mfma_f32_16x16x32_bf16(a[i], b[j], acc[i][j], 0, 0, 0);
                    else
                        acc[i][j] = __builtin_amdgcn_mfma_f32_16x16x32_bf16(b[j], a[i], acc[i][j], 0, 0, 0);
                }
        }
    }

    __syncthreads();   // k-loop LDS reads done; reuse Sh as 128x128 C-tile

    const float qscale = 0.04419417382415922f * 1.4426950408889634f; // 1/sqrt(512)*log2e
    if (z == 2) {
        // natural C: lane holds C[m = wy*64+i*16+quad*4+reg][n = wx*64+j*16+r16]
        // store TRANSPOSED into Sh[n][m] (4 consec m per uint2)
        #pragma unroll
        for (int j = 0; j < 4; ++j) {
            const int nloc = wx*64 + j*16 + r16;
            const float bz = bias[n0 + nloc];
            #pragma unroll
            for (int i = 0; i < 4; ++i) {
                const int chunk = wy*8 + i*2 + (quad>>1);
                const int off   = (quad & 1) * 4;
                unsigned short r4[4];
                #pragma unroll
                for (int reg = 0; reg < 4; ++reg)
                    r4[reg] = f2bf(acc[i][j][reg] + bz);
                *(uint2*)&Sh[nloc*128 + ((chunk ^ (nloc & 7))*8) + off] = *(const uint2*)r4;
            }
        }
    } else {
        // swapped C^T: lane holds C^T[n = wx*64+j*16+quad*4+reg][m = wy*64+i*16+r16]
        // store into Sh[m][n] (4 consec n per uint2)
        #pragma unroll
        for (int j = 0; j < 4; ++j) {
            const int nbase = wx*64 + j*16 + quad*4;
            const float4 bz4 = *(const float4*)&bias[n0 + nbase];
            const int chunk = wx*8 + j*2 + (quad>>1);
            const int off   = (quad & 1) * 4;
            #pragma unroll
            for (int i = 0; i < 4; ++i) {
                const int mloc = wy*64 + i*16 + r16;
                float v0 = acc[i][j][0] + bz4.x;
                float v1 = acc[i][j][1] + bz4.y;
                float v2 = acc[i][j][2] + bz4.z;
                float v3 = acc[i][j][3] + bz4.w;
                if (z == 0) { v0 *= qscale; v1 *= qscale; v2 *= qscale; v3 *= qscale; }
                unsigned short r4[4] = { f2bf(v0), f2bf(v1), f2bf(v2), f2bf(v3) };
                *(uint2*)&Sh[mloc*128 + ((chunk ^ (mloc & 7))*8) + off] = *(const uint2*)r4;
            }
        }
    }
    __syncthreads();

    // COALESCED stores: consecutive lanes -> consecutive 16B chunks
    if (z == 2) {
        // Sh[n(hd-row)][m(s)]: 128 rows x 16 chunks; 4 x 256B runs per inst
        const int b_ = m0 >> 12, s0_ = m0 & (SS-1);
        #pragma unroll
        for (int p = 0; p < 8; ++p) {
            const int f = p*256 + tid;
            const int nrow = f >> 4;          // 0..127
            const int mch  = f & 15;          // 0..15
            bf16x8 v = *(const bf16x8*)&Sh[nrow*128 + ((mch ^ (nrow & 7))*8)];
            const int ng = n0 + nrow;
            const int h = ng >> 6, hd = ng & 63;
            *(bf16x8*)&dst[((size_t)(b_*HH + h)*HD + hd)*SS + s0_ + mch*8] = v;
        }
    } else {
        // Sh[m(s-row)][n]: 128 rows x 2 h-halves x 8 chunks; 1KB-contig per inst
        #pragma unroll
        for (int p = 0; p < 8; ++p) {
            const int f = p*256 + tid;
            const int hh  = f >> 10;          // 0..1
            const int rem = f & 1023;
            const int sr  = rem >> 3;         // 0..127
            const int ch  = rem & 7;
            bf16x8 v = *(const bf16x8*)&Sh[sr*128 + (((hh*8 + ch) ^ (sr & 7))*8)];
            const int mg = m0 + sr;
            const int b_ = mg >> 12, s_ = mg & (SS-1);
            const int hg = (n0 >> 6) + hh;
            *(bf16x8*)&dst[((size_t)(b_*HH + hg)*SS + s_)*HD + ch*8] = v;
        }
    }
}

// ---------------------------------------------------------------------------
// MFMA flash attention with DMA double-buffered K/V staging.
// Block = 4 waves, q-block 128 (wave w owns 32 q = qb*128 + w*32 ..+31).
// Per 64-key tile: all waves co-stage K -> Ks[buf], V^T -> Vs[buf] via
// global_load_lds (no VGPR cost -> prefetch cannot be sunk by regalloc);
// loop = { barrier(drains DMA t); issue DMA t+1 into buf^1; compute t }.
// S^T = K Q^T -> exp2 (fixed max) -> P via wave-private LDS -> O^T += V^T P^T.
// grid 512 (bh in low 4 bits; heavy q-chunks first), block 256.
// ---------------------------------------------------------------------------
__global__ __launch_bounds__(256)
void attn_mfma(const unsigned short* __restrict__ ws, float* __restrict__ out) {
    const int bh   = blockIdx.x & 15;
    const int qb   = 31 - (blockIdx.x >> 4);    // heavy-first
    const int tid  = threadIdx.x;
    const int w    = tid >> 6, l = tid & 63;
    const int quad = l >> 4,  r16 = l & 15;
    const int qlo  = qb*128 + w*32;
    const int ntiles = 2*qb + 2;
    const int tdiag  = 2*qb + (w >> 1);
    const int qoff   = 32*(w & 1);

    const unsigned short* Qg  = ws;             // pre-scaled by log2e/sqrt(512)
    const unsigned short* Kg  = ws + (size_t)MSD;
    const unsigned short* Vtg = ws + 2*(size_t)MSD;

    __shared__ __align__(16) unsigned short Ks[2][64*64];
    __shared__ __align__(16) unsigned short Vs[2][64*64];
    __shared__ __align__(16) unsigned int   Ps[4][32*36];
    unsigned int* PsW = Ps[w];

    const size_t kbase = (size_t)bh*SS*HD;
    const size_t vbase = (size_t)bh*HD*SS;

    // Q B-frags: lane holds Q[q = qlo+nt*16+r16][d = kc*32+quad*8+j]
    bf16x8 bqf[2][2];
    #pragma unroll
    for (int nt = 0; nt < 2; ++nt)
        #pragma unroll
        for (int kc = 0; kc < 2; ++kc)
            bqf[nt][kc] = *(const bf16x8*)&Qg[kbase + (size_t)(qlo + nt*16 + r16)*HD + kc*32 + quad*8];

    f32x4 od[4][2];   // O^T accum: [mt -> d][nt -> q]
    #pragma unroll
    for (int mt = 0; mt < 4; ++mt)
        #pragma unroll
        for (int nt = 0; nt < 2; ++nt) od[mt][nt] = (f32x4){0.f,0.f,0.f,0.f};
    float lsum[2] = {0.f, 0.f};

    // staging: wave w stages rows [w*16, w*16+16) of K and V^T (2 GLD16 each)
    const int sr8 = l >> 3, sc = l & 7;

    // prologue: stage tile 0 into buf 0
    #pragma unroll
    for (int u = 0; u < 2; ++u) {
        const int row = w*16 + u*8 + sr8;
        const int c   = sc ^ (row & 7);
        GLD16(&Kg [kbase + (size_t)row*HD + c*8], &Ks[0][(w*16 + u*8)*64]);
        GLD16(&Vtg[vbase + (size_t)row*SS + c*8], &Vs[0][(w*16 + u*8)*64]);
    }

    for (int t = 0; t < ntiles; ++t) {
        __syncthreads();                        // drains DMA(t) for all waves

        if (t + 1 < ntiles) {                   // issue DMA(t+1) into other buf
            const int jb1 = (t + 1)*64;
            const int b1  = (t + 1) & 1;
            #pragma unroll
            for (int u = 0; u < 2; ++u) {
                const int row = w*16 + u*8 + sr8;
                const int c   = sc ^ (row & 7);
                GLD16(&Kg [kbase + (size_t)(jb1 + row)*HD + c*8], &Ks[b1][(w*16 + u*8)*64]);
                GLD16(&Vtg[vbase + (size_t)row*SS + jb1 + c*8],   &Vs[b1][(w*16 + u*8)*64]);
            }
        }

        if (t <= tdiag) {
            const unsigned short* Kb = Ks[t & 1];
            const unsigned short* Vb = Vs[t & 1];

            // ---- S^T = K Q^T : lane holds S^T[key = mt*16+quad*4+reg][q = nt*16+r16]
            f32x4 z[4][2];
            #pragma unroll
            for (int mt = 0; mt < 4; ++mt) {
                const int row = mt*16 + r16;
                bf16x8 ak0 = *(const bf16x8*)&Kb[row*64 + ((quad     ^ (row&7))*8)];
                bf16x8 ak1 = *(const bf16x8*)&Kb[row*64 + (((4+quad) ^ (row&7))*8)];
                #pragma unroll
                for (int nt = 0; nt < 2; ++nt) {
                    z[mt][nt] = __builtin_amdgcn_mfma_f32_16x16x32_bf16(ak0, bqf[nt][0],
                                    (f32x4){0.f,0.f,0.f,0.f}, 0, 0, 0);
                    z[mt][nt] = __builtin_amdgcn_mfma_f32_16x16x32_bf16(ak1, bqf[nt][1], z[mt][nt], 0, 0, 0);
                }
            }

            if (t == tdiag) {   // causal mask on the diagonal tile
                #pragma unroll
                for (int mt = 0; mt < 4; ++mt)
                    #pragma unroll
                    for (int nt = 0; nt < 2; ++nt)
                        #pragma unroll
                        for (int reg = 0; reg < 4; ++reg)
                            if (mt*16 + quad*4 + reg > qoff + nt*16 + r16)
                                z[mt][nt][reg] = -1e30f;
            }

            // ---- P = exp2(z); accumulate l; packed b64 stores into wave-private Ps
            #pragma unroll
            for (int mt = 0; mt < 4; ++mt)
                #pragma unroll
                for (int nt = 0; nt < 2; ++nt) {
                    #pragma unroll
                    for (int reg = 0; reg < 4; ++reg) {
                        z[mt][nt][reg] = exp2f(z[mt][nt][reg]);
                        lsum[nt] += z[mt][nt][reg];
                    }
                    uint2 pk;
                    pk.x = pk2bf(z[mt][nt][0], z[mt][nt][1]);
                    pk.y = pk2bf(z[mt][nt][2], z[mt][nt][3]);
                    *(uint2*)&PsW[(nt*16 + r16)*36 + mt*8 + quad*2] = pk;
                }

            asm volatile("s_waitcnt lgkmcnt(0)" ::: "memory");  // wave-private round-trip

            // ---- O^T += V^T P^T
            bf16x8 pf[2][2];
            #pragma unroll
            for (int nt = 0; nt < 2; ++nt)
                #pragma unroll
                for (int kc = 0; kc < 2; ++kc)
                    pf[nt][kc] = *(const bf16x8*)&PsW[(nt*16 + r16)*36 + kc*16 + quad*4];

            #pragma unroll
            for (int mt = 0; mt < 4; ++mt) {
                const int row = mt*16 + r16;
                bf16x8 av0 = *(const bf16x8*)&Vb[row*64 + ((quad     ^ (row&7))*8)];
                bf16x8 av1 = *(const bf16x8*)&Vb[row*64 + (((4+quad) ^ (row&7))*8)];
                #pragma unroll
                for (int nt = 0; nt < 2; ++nt) {
                    od[mt][nt] = __builtin_amdgcn_mfma_f32_16x16x32_bf16(av0, pf[nt][0], od[mt][nt], 0, 0, 0);
                    od[mt][nt] = __builtin_amdgcn_mfma_f32_16x16x32_bf16(av1, pf[nt][1], od[mt][nt], 0, 0, 0);
                }
            }
        }
    }

    // ---- l: sum the 4 quad-partials per q
    #pragma unroll
    for (int nt = 0; nt < 2; ++nt) {
        lsum[nt] += __shfl_xor(lsum[nt], 16);
        lsum[nt] += __shfl_xor(lsum[nt], 32);
    }

    const int b_ = bh >> 3, h = bh & 7;
    #pragma unroll
    for (int nt = 0; nt < 2; ++nt) {
        const float inv = 1.0f / lsum[nt];
        const int q = qlo + nt*16 + r16;
        float* op = out + ((size_t)(b_*SS + q))*DD + h*HD;
        #pragma unroll
        for (int mt = 0; mt < 4; ++mt) {
            float4 tt;
            tt.x = od[mt][nt][0]*inv; tt.y = od[mt][nt][1]*inv;
            tt.z = od[mt][nt][2]*inv; tt.w = od[mt][nt][3]*inv;
            *(float4*)&op[mt*16 + quad*4] = tt;
        }
    }
}

extern "C" void kernel_launch(void* const* d_in, const int* in_sizes, int n_in,
                              void* d_out, int out_size, void* d_ws, size_t ws_size,
                              hipStream_t stream) {
    const float* x  = (const float*)d_in[0];
    const float* Wq = (const float*)d_in[1];
    const float* bq = (const float*)d_in[2];
    const float* Wk = (const float*)d_in[3];
    const float* bk = (const float*)d_in[4];
    const float* Wv = (const float*)d_in[5];
    const float* bv = (const float*)d_in[6];
    float* out = (float*)d_out;
    unsigned short* ws = (unsigned short*)d_ws;

    const int nconv = (MSD/8 + 3*WSZ/8 + 255) / 256;
    convert_bf16<<<nconv, 256, 0, stream>>>(x, Wq, Wk, Wv, ws);

    dim3 ggrid(DD/128, (BB*SS)/128, 3);           // (4, 64, 3)
    qkv_mfma<<<ggrid, 256, 0, stream>>>(bq, bk, bv, ws);

    attn_mfma<<<512, 256, 0, stream>>>(ws, out);
}